// Round 4
// baseline (179.105 us; speedup 1.0000x reference)
//
#include <hip/hip_runtime.h>
#include <stdint.h>
#include <stddef.h>

// Problem constants (fixed by the reference):
//   x:[B=65536][D=128] f32, E:[C=64][L=64][D=128] f32, counts:[64][64] f32
//   out0 = max_l cos(x_b, E_{c,l})  [B][C]
//   out1 = counts + bincount of argmax_l  [C][L]
#define D      128
#define NCATS  64
#define NLEAF  64
#define NC_BLK 8     // categories per block (c-split x8)
#define BM     512   // rows per block (8 waves x 64 batch cols)
#define BIAS   32.0f // dot ~ N(0,1) -> biased value positive -> uint order == float order

typedef _Float16 half8_t  __attribute__((ext_vector_type(8)));
typedef _Float16 half4h_t __attribute__((ext_vector_type(4)));
typedef float    float4_t __attribute__((ext_vector_type(4)));

__device__ __forceinline__ void async_ld16(const void* g, void* l) {
  __builtin_amdgcn_global_load_lds((const __attribute__((address_space(1))) uint32_t*)g,
                                   (__attribute__((address_space(3))) uint32_t*)l,
                                   16, 0, 0);
}

// Per-wave counted vmem wait (literal N). "memory" clobber orders the
// following ds_reads (they are memory ops, so this is sufficient; rule #18
// only bites for register-only consumers).
#define WAITV(n) asm volatile("s_waitcnt vmcnt(" #n ")" ::: "memory")

// Each wave redundantly DMAs the WHOLE 16KB tile (16 instrs x 64 lanes x 16B)
// so tile-ready is per-wave vmcnt state — no cross-wave sync needed to read.
// 8 waves write identical bytes to the same LDS lines (benign). L2-sourced.
#define ISSUE_TILE(ti, slot)                                                  \
  {                                                                           \
    const char* g_ = e16 + (size_t)(c_base + (ti)) * 16384 + lane * 16;       \
    char* l_ = &ebuf[slot][lane * 16];                                        \
    _Pragma("unroll")                                                         \
    for (int j_ = 0; j_ < 16; ++j_) async_ld16(g_ + j_ * 1024, l_ + j_ * 1024);\
  }

// ---------------------------------------------------------------------------
// Prep (R2/R7-verified): E rows -> unit-normalized fp16 with the LDS
// bank-conflict swizzle pre-baked (chunk' = chunk ^ (row&7)) so main staging
// is linear. Also seeds counts_out from the input buffer (d_out is poisoned).
// ---------------------------------------------------------------------------
__global__ __launch_bounds__(256) void prep_e_kernel(const float* __restrict__ e,
                                                     char* __restrict__ e16,
                                                     const float* __restrict__ cin,
                                                     float* __restrict__ counts_out) {
  const int t  = threadIdx.x;
  const int rl = t >> 4;  // row within this block's 16
  const int cc = t & 15;  // 16B chunk (8 halfs) within row
  const int row = blockIdx.x * 16 + rl;
  const float* src = e + (size_t)row * D + cc * 8;
  float4_t v0 = *(const float4_t*)src;
  float4_t v1 = *(const float4_t*)(src + 4);
  float ss = v0.x*v0.x + v0.y*v0.y + v0.z*v0.z + v0.w*v0.w +
             v1.x*v1.x + v1.y*v1.y + v1.z*v1.z + v1.w*v1.w;
  ss += __shfl_xor(ss, 1);
  ss += __shfl_xor(ss, 2);
  ss += __shfl_xor(ss, 4);
  ss += __shfl_xor(ss, 8);
  const float inv = 1.0f / fmaxf(sqrtf(ss), 1e-8f);
  half8_t h;
  h[0] = (_Float16)(v0.x * inv); h[1] = (_Float16)(v0.y * inv);
  h[2] = (_Float16)(v0.z * inv); h[3] = (_Float16)(v0.w * inv);
  h[4] = (_Float16)(v1.x * inv); h[5] = (_Float16)(v1.y * inv);
  h[6] = (_Float16)(v1.z * inv); h[7] = (_Float16)(v1.w * inv);
  const int dc = cc ^ (rl & 7);  // swizzle: row&7 == rl&7 (16-row blocks)
  *(half8_t*)(e16 + (size_t)row * 256 + dc * 16) = h;
  if (blockIdx.x < (NCATS * NLEAF) / 256)
    counts_out[blockIdx.x * 256 + t] = cin[blockIdx.x * 256 + t];
}

// ---------------------------------------------------------------------------
// Main (R12): R9 chassis (verified layouts, 60-VGPR pack) + BARRIER-FREE ci
// loop. Evidence: MfmaUtil==VALUBusy==26% in R9/R11, insensitive to occupancy
// 21<->41% -> common serial cadence = per-ci __syncthreads (+vmcnt0 drain)
// convoying all 8 waves. R10 showed exposed per-use global latency is worse
// (145us) -> keep LDS, but gate tiles per-wave:
//  * ebuf[4] slots (64KB); each wave DMAs full tiles redundantly; counted
//    WAITV(32/16/0) schedule keeps 2-3 tiles in flight, never over-drains.
//  * ONE mid-loop barrier (slot reuse at ci=4; outstanding==0 there).
//  * Writers spread to all 64 lanes (lane(q,wl) writes nt=q; pk[q]/inv_x[q]
//    via constant-index selects): 1 stage-write + 1 hist-atomic instr, not 4.
//  * setprio(1) around MFMA: waves now phase-diverse (T5's regime).
//  * LDS 75.5KB -> 2 blocks/CU (LDS-limited; VGPR<=128 fine -> (512,2)).
// ---------------------------------------------------------------------------
__global__ __launch_bounds__(512, 2) void main_kernel(const float* __restrict__ x,
                                                      const char* __restrict__ e16,
                                                      float* __restrict__ cos_out,
                                                      float* __restrict__ counts_out) {
  __shared__ __align__(16) char ebuf[4][16384];          // 64 KB, swizzled rows
  __shared__ unsigned hist[NC_BLK * NLEAF];              // 2 KB
  __shared__ __align__(16) _Float16 stage[BM * 8];       // 8 KB, 16 B/row

  const int tid  = threadIdx.x;
  const int w    = tid >> 6;    // wave 0..7
  const int lane = tid & 63;
  const int q    = lane >> 4;   // MFMA quad
  const int wl   = lane & 15;

  // XCD-aware decode: the 8 c-split sharers of a row-block land on one XCD.
  const int rb     = ((blockIdx.x >> 6) << 3) + (blockIdx.x & 7);
  const int c_base = ((blockIdx.x >> 3) & 7) * NC_BLK;
  const int b_base = rb * BM;

  for (int i = tid; i < NC_BLK * NLEAF; i += 512) hist[i] = 0;

  // B = x fragments (verified lane layout: B[n=lane&15][k=quad*8+j]):
  // tile nt covers batch rows b_base + w*64 + nt*16 + [0,16).
  half8_t bfrag[4][4];
  float inv_x[4];
#pragma unroll
  for (int nt = 0; nt < 4; ++nt) {
    const int row = b_base + w * 64 + nt * 16 + wl;
    const float* xr = x + (size_t)row * D;
    float ss = 0.f;
#pragma unroll
    for (int s = 0; s < 4; ++s) {
      const float* p = xr + s * 32 + q * 8;
      float4_t v0 = *(const float4_t*)p;
      float4_t v1 = *(const float4_t*)(p + 4);
      half8_t h;
      h[0] = (_Float16)v0.x; h[1] = (_Float16)v0.y;
      h[2] = (_Float16)v0.z; h[3] = (_Float16)v0.w;
      h[4] = (_Float16)v1.x; h[5] = (_Float16)v1.y;
      h[6] = (_Float16)v1.z; h[7] = (_Float16)v1.w;
      bfrag[nt][s] = h;
      ss += v0.x*v0.x + v0.y*v0.y + v0.z*v0.z + v0.w*v0.w +
            v1.x*v1.x + v1.y*v1.y + v1.z*v1.z + v1.w*v1.w;
    }
    ss += __shfl_xor(ss, 16);  // sum across the 4 quads holding this row
    ss += __shfl_xor(ss, 32);
    inv_x[nt] = 1.0f / fmaxf(sqrtf(ss), 1e-8f);
  }

  // A = E LDS addresses (rt = leaf tile): row (rt*16+wl), chunk
  // (q+4s)^(wl&7) [prep pre-swizzled].
  int rowbase[4], xoff[4];
#pragma unroll
  for (int rt = 0; rt < 4; ++rt) rowbase[rt] = (rt * 16 + wl) * 256;
#pragma unroll
  for (int s = 0; s < 4; ++s) xoff[s] = ((q + 4 * s) ^ (wl & 7)) * 16;

  const unsigned idq = (unsigned)(q << 2);  // leaf-index bits {2,3} (lane const)
  const float4_t bias4 = {BIAS, BIAS, BIAS, BIAS};

  __syncthreads();  // hist init visible; also guarantees vmcnt==0 here

  // Prologue: per-wave DMA of tiles 0,1,2 into slots 0,1,2 (48 outstanding).
  ISSUE_TILE(0, 0);
  ISSUE_TILE(1, 1);
  ISSUE_TILE(2, 2);

#pragma unroll
  for (int ci = 0; ci < NC_BLK; ++ci) {
    const char* cur = ebuf[ci & 3];

    // Per-wave counted tile gating (16 loads/tile, own-wave DMA only):
    if      (ci == 0) { WAITV(32); ISSUE_TILE(3, 3); }  // t0 ready; 48 in flight
    else if (ci == 1) { WAITV(32); }                    // t1 ready
    else if (ci == 2) { WAITV(16); }                    // t2 ready
    else if (ci == 3) { WAITV(0);  }                    // t3 ready; pipe empty
    else if (ci == 4) { WAITV(32); ISSUE_TILE(7, 3); }  // t4 ready
    else if (ci == 5) { WAITV(32); }                    // t5 ready
    else if (ci == 6) { WAITV(16); }                    // t6 ready
    else              { WAITV(0);  }                    // t7 ready

    // rt-outer: acc[4] (one per batch tile nt) live at a time. C/D layout:
    // col = lane&15 = batch-within-tile, row = q*4+reg = leaf-within-tile.
    // Keys carry leaf idx bits {0,1}=reg, {4,5}=rt at pack time; bits {2,3}
    // (=q) are zero in-lane and OR'd once before the cross-lane combine.
    unsigned pk[4];
    __builtin_amdgcn_s_setprio(1);
#pragma unroll
    for (int rt = 0; rt < 4; ++rt) {
      float4_t acc[4];
#pragma unroll
      for (int s = 0; s < 4; ++s) {
        half8_t ef = *(const half8_t*)(cur + rowbase[rt] + xoff[s]);
#pragma unroll
        for (int nt = 0; nt < 4; ++nt)
          acc[nt] = __builtin_amdgcn_mfma_f32_16x16x32_f16(
              ef, bfrag[nt][s], (s == 0) ? bias4 : acc[nt], 0, 0, 0);
      }
#pragma unroll
      for (int nt = 0; nt < 4; ++nt)
#pragma unroll
        for (int reg = 0; reg < 4; ++reg) {
          unsigned k = (__float_as_uint(acc[nt][reg]) & 0xFFFFFFC0u) |
                       (unsigned)(rt * 16 + reg);
          if (rt == 0 && reg == 0) pk[nt] = k;
          else                     pk[nt] = (pk[nt] > k) ? pk[nt] : k;
        }
    }
    __builtin_amdgcn_s_setprio(0);

    // Cross-lane: combine the 4 quads of this batch col. EXPLICIT TEMPS,
    // unconditional shuffles (R3 lesson: never a cross-lane op in a ternary).
#pragma unroll
    for (int nt = 0; nt < 4; ++nt) {
      unsigned v = pk[nt] | idq;
      unsigned t = (unsigned)__shfl_xor((int)v, 16);
      v = (v > t) ? v : t;
      t = (unsigned)__shfl_xor((int)v, 32);
      v = (v > t) ? v : t;
      pk[nt] = v;  // uniform across the 4 quads of this wl
    }

    // Writers spread over all 64 lanes: lane (q,wl) handles nt=q. pk[q] is
    // quad-uniform; inv_x[q] is wl-determined (q-independent) -> every lane
    // holds the right inv. Constant-index selects (no runtime array index).
    {
      const unsigned pk01 = (q == 0) ? pk[0] : pk[1];
      const unsigned pk23 = (q == 2) ? pk[2] : pk[3];
      const unsigned pkq  = (q < 2) ? pk01 : pk23;
      const float    iv01 = (q == 0) ? inv_x[0] : inv_x[1];
      const float    iv23 = (q == 2) ? inv_x[2] : inv_x[3];
      const float    invq = (q < 2) ? iv01 : iv23;
      const float val = (__uint_as_float(pkq & 0xFFFFFFC0u) - BIAS) * invq;
      stage[tid * 8 + ci] = (_Float16)val;  // row w*64+q*16+wl == w*64+lane
      atomicAdd(&hist[ci * NLEAF + (int)(pkq & 63u)], 1u);
    }

    // Slot reuse point: all waves must be done reading tiles 0-3 before we
    // DMA tiles 4-6 into slots 0-2. Outstanding vmcnt==0 here (WAITV(0) at
    // ci==3), so this barrier drains nothing extra.
    if (ci == 3) {
      __syncthreads();
      ISSUE_TILE(4, 0);
      ISSUE_TILE(5, 1);
      ISSUE_TILE(6, 2);
    }
  }

  __syncthreads();  // stage writes visible to all

  // Coalesced cos flush: rows [b_base,+512) x cols [c_base,+8).
  // stage byte addr = 8*id -> contiguous b64 reads, conflict-free.
#pragma unroll
  for (int k = 0; k < 2; ++k) {
    const int id = k * 512 + tid;
    const int r  = id >> 1;
    const int c0 = (id & 1) * 4;
    half4h_t h = *(const half4h_t*)&stage[r * 8 + c0];
    float4_t v;
    v.x = (float)h[0]; v.y = (float)h[1]; v.z = (float)h[2]; v.w = (float)h[3];
    *(float4_t*)&cos_out[(size_t)(b_base + r) * NCATS + c_base + c0] = v;
  }

  // Flush histogram (exact: integer-valued float atomics).
  for (int i = tid; i < NC_BLK * NLEAF; i += 512) {
    const unsigned v = hist[i];
    if (v) atomicAdd(&counts_out[c_base * NLEAF + i], (float)v);
  }
}

extern "C" void kernel_launch(void* const* d_in, const int* in_sizes, int n_in,
                              void* d_out, int out_size, void* d_ws, size_t ws_size,
                              hipStream_t stream) {
  const float* x   = (const float*)d_in[0];
  const float* e   = (const float*)d_in[1];
  const float* cin = (const float*)d_in[2];

  const int B = in_sizes[0] / D;                 // 65536
  const int erows = in_sizes[1] / D;             // 4096
  float* cos_out = (float*)d_out;                // [B][64]
  float* counts_out = cos_out + (size_t)B * NCATS;
  char* e16 = (char*)d_ws;                       // 4096*256B = 1 MB swizzled fp16 E

  prep_e_kernel<<<erows / 16, 256, 0, stream>>>(e, e16, cin, counts_out);
  main_kernel<<<(B / BM) * (NCATS / NC_BLK), 512, 0, stream>>>(x, e16, cos_out, counts_out);
}

// Round 6
// 157.316 us; speedup vs baseline: 1.1385x; 1.1385x over previous
//
#include <hip/hip_runtime.h>
#include <stdint.h>
#include <stddef.h>

// Problem constants (fixed by the reference):
//   x:[B=65536][D=128] f32, E:[C=64][L=64][D=128] f32, counts:[64][64] f32
//   out0 = max_l cos(x_b, E_{c,l})  [B][C]
//   out1 = counts + bincount of argmax_l  [C][L]
#define D      128
#define NCATS  64
#define NLEAF  64
#define NC_BLK 4     // categories per block (c-split x16): ALL tiles LDS-resident
#define BM     512   // rows per block (8 waves x 64 batch cols)
#define BIAS   32.0f // dot ~ N(0,1) -> biased value positive -> uint order == float order

typedef _Float16 half8_t  __attribute__((ext_vector_type(8)));
typedef _Float16 half4h_t __attribute__((ext_vector_type(4)));
typedef float    float4_t __attribute__((ext_vector_type(4)));

__device__ __forceinline__ void async_ld16(const void* g, void* l) {
  __builtin_amdgcn_global_load_lds((const __attribute__((address_space(1))) uint32_t*)g,
                                   (__attribute__((address_space(3))) uint32_t*)l,
                                   16, 0, 0);
}

// ---------------------------------------------------------------------------
// Prep (R2/R7-verified): E rows -> unit-normalized fp16 with the LDS
// bank-conflict swizzle pre-baked (chunk' = chunk ^ (row&7)) so main staging
// is linear. Also seeds counts_out from the input buffer (d_out is poisoned).
// ---------------------------------------------------------------------------
__global__ __launch_bounds__(256) void prep_e_kernel(const float* __restrict__ e,
                                                     char* __restrict__ e16,
                                                     const float* __restrict__ cin,
                                                     float* __restrict__ counts_out) {
  const int t  = threadIdx.x;
  const int rl = t >> 4;  // row within this block's 16
  const int cc = t & 15;  // 16B chunk (8 halfs) within row
  const int row = blockIdx.x * 16 + rl;
  const float* src = e + (size_t)row * D + cc * 8;
  float4_t v0 = *(const float4_t*)src;
  float4_t v1 = *(const float4_t*)(src + 4);
  float ss = v0.x*v0.x + v0.y*v0.y + v0.z*v0.z + v0.w*v0.w +
             v1.x*v1.x + v1.y*v1.y + v1.z*v1.z + v1.w*v1.w;
  ss += __shfl_xor(ss, 1);
  ss += __shfl_xor(ss, 2);
  ss += __shfl_xor(ss, 4);
  ss += __shfl_xor(ss, 8);
  const float inv = 1.0f / fmaxf(sqrtf(ss), 1e-8f);
  half8_t h;
  h[0] = (_Float16)(v0.x * inv); h[1] = (_Float16)(v0.y * inv);
  h[2] = (_Float16)(v0.z * inv); h[3] = (_Float16)(v0.w * inv);
  h[4] = (_Float16)(v1.x * inv); h[5] = (_Float16)(v1.y * inv);
  h[6] = (_Float16)(v1.z * inv); h[7] = (_Float16)(v1.w * inv);
  const int dc = cc ^ (rl & 7);  // swizzle: row&7 == rl&7 (16-row blocks)
  *(half8_t*)(e16 + (size_t)row * 256 + dc * 16) = h;
  if (blockIdx.x < (NCATS * NLEAF) / 256)
    counts_out[blockIdx.x * 256 + t] = cin[blockIdx.x * 256 + t];
}

// ---------------------------------------------------------------------------
// Main (R13): R9 chassis (verified layouts, 60-VGPR pack, (512,3)) with the
// per-ci barrier CONVOY removed the cheap way:
//  * NC_BLK=4 -> all 4 E-tiles (64KB) staged ONCE (each wave DMAs 8KB, no
//    redundancy), ONE barrier, then the whole ci loop is barrier-free and
//    wait-free. Compiler can software-pipeline ACROSS ci iterations.
//    (R12 lesson: redundant per-wave DMA + reg balloon = -16%; this keeps
//    DMA minimal and the R9 register shape.)
//  * Evidence base: R11/R12 showed occupancy 21<->41% changes time only
//    5-15% -> not wave-starved; MfmaUtil pinned ~25% with per-SIMD matrix
//    floor 33% at this shape -> the barrier convoy is the residue.
//  * LDS 69KB -> 2 blocks/CU (LDS-capped). Grid 2048, 8/CU -> good balance.
//  * XCD decode: per XCD, 16 rb x 16 c; x working set 16x256KB = 4MB = L2.
//  * setprio(1) around MFMA: convoy-free waves have phase diversity (T5).
// ---------------------------------------------------------------------------
__global__ __launch_bounds__(512, 3) void main_kernel(const float* __restrict__ x,
                                                      const char* __restrict__ e16,
                                                      float* __restrict__ cos_out,
                                                      float* __restrict__ counts_out) {
  __shared__ __align__(16) char ebuf[NC_BLK][16384];     // 64 KB, swizzled rows
  __shared__ unsigned hist[NC_BLK * NLEAF];              // 1 KB
  __shared__ __align__(16) _Float16 stage[BM * NC_BLK];  // 4 KB, 8 B/row

  const int tid  = threadIdx.x;
  const int w    = tid >> 6;    // wave 0..7
  const int lane = tid & 63;
  const int q    = lane >> 4;   // MFMA quad
  const int wl   = lane & 15;

  // XCD-aware decode: bid = c_idx*128 + rb_local*8 + xcd.
  const int xcd    = blockIdx.x & 7;
  const int rb     = xcd * 16 + ((blockIdx.x >> 3) & 15);
  const int c_base = (blockIdx.x >> 7) * NC_BLK;
  const int b_base = rb * BM;

  // Stage ALL 4 tiles now: wave w -> tile w>>1, half w&1 (8KB each, 8 loads).
  {
    const char* g = e16 + (size_t)(c_base + (w >> 1)) * 16384 + (w & 1) * 8192 + lane * 16;
    char* l = &ebuf[w >> 1][(w & 1) * 8192 + lane * 16];
#pragma unroll
    for (int j = 0; j < 8; ++j) async_ld16(g + j * 1024, l + j * 1024);
  }

  for (int i = tid; i < NC_BLK * NLEAF; i += 512) hist[i] = 0;

  // B = x fragments (verified lane layout: B[n=lane&15][k=quad*8+j]):
  // tile nt covers batch rows b_base + w*64 + nt*16 + [0,16).
  // These global loads overlap the DMA fill latency.
  half8_t bfrag[4][4];
  float inv_x[4];
#pragma unroll
  for (int nt = 0; nt < 4; ++nt) {
    const int row = b_base + w * 64 + nt * 16 + wl;
    const float* xr = x + (size_t)row * D;
    float ss = 0.f;
#pragma unroll
    for (int s = 0; s < 4; ++s) {
      const float* p = xr + s * 32 + q * 8;
      float4_t v0 = *(const float4_t*)p;
      float4_t v1 = *(const float4_t*)(p + 4);
      half8_t h;
      h[0] = (_Float16)v0.x; h[1] = (_Float16)v0.y;
      h[2] = (_Float16)v0.z; h[3] = (_Float16)v0.w;
      h[4] = (_Float16)v1.x; h[5] = (_Float16)v1.y;
      h[6] = (_Float16)v1.z; h[7] = (_Float16)v1.w;
      bfrag[nt][s] = h;
      ss += v0.x*v0.x + v0.y*v0.y + v0.z*v0.z + v0.w*v0.w +
            v1.x*v1.x + v1.y*v1.y + v1.z*v1.z + v1.w*v1.w;
    }
    ss += __shfl_xor(ss, 16);  // sum across the 4 quads holding this row
    ss += __shfl_xor(ss, 32);
    inv_x[nt] = 1.0f / fmaxf(sqrtf(ss), 1e-8f);
  }

  // A = E LDS addresses (rt = leaf tile): row (rt*16+wl), chunk
  // (q+4s)^(wl&7) [prep pre-swizzled].
  int rowbase[4], xoff[4];
#pragma unroll
  for (int rt = 0; rt < 4; ++rt) rowbase[rt] = (rt * 16 + wl) * 256;
#pragma unroll
  for (int s = 0; s < 4; ++s) xoff[s] = ((q + 4 * s) ^ (wl & 7)) * 16;

  const unsigned idq = (unsigned)(q << 2);  // leaf-index bits {2,3} (lane const)
  const float4_t bias4 = {BIAS, BIAS, BIAS, BIAS};

  __syncthreads();  // ONE barrier: drains tile DMA (vmcnt0) + hist init

  // ----- barrier-free, wait-free ci loop -----
#pragma unroll
  for (int ci = 0; ci < NC_BLK; ++ci) {
    const char* cur = ebuf[ci];

    // rt-outer: acc[4] (one per batch tile nt) live at a time. C/D layout:
    // col = lane&15 = batch-within-tile, row = q*4+reg = leaf-within-tile.
    // Keys carry leaf idx bits {0,1}=reg, {4,5}=rt at pack time; bits {2,3}
    // (=q) are zero in-lane and OR'd once before the cross-lane combine.
    unsigned pk[4];
    __builtin_amdgcn_s_setprio(1);
#pragma unroll
    for (int rt = 0; rt < 4; ++rt) {
      float4_t acc[4];
#pragma unroll
      for (int s = 0; s < 4; ++s) {
        half8_t ef = *(const half8_t*)(cur + rowbase[rt] + xoff[s]);
#pragma unroll
        for (int nt = 0; nt < 4; ++nt)
          acc[nt] = __builtin_amdgcn_mfma_f32_16x16x32_f16(
              ef, bfrag[nt][s], (s == 0) ? bias4 : acc[nt], 0, 0, 0);
      }
#pragma unroll
      for (int nt = 0; nt < 4; ++nt)
#pragma unroll
        for (int reg = 0; reg < 4; ++reg) {
          unsigned k = (__float_as_uint(acc[nt][reg]) & 0xFFFFFFC0u) |
                       (unsigned)(rt * 16 + reg);
          if (rt == 0 && reg == 0) pk[nt] = k;
          else                     pk[nt] = (pk[nt] > k) ? pk[nt] : k;
        }
    }
    __builtin_amdgcn_s_setprio(0);

    // Cross-lane: combine the 4 quads of this batch col. EXPLICIT TEMPS,
    // unconditional shuffles (R3 lesson: never a cross-lane op in a ternary).
#pragma unroll
    for (int nt = 0; nt < 4; ++nt) {
      unsigned v = pk[nt] | idq;
      unsigned t = (unsigned)__shfl_xor((int)v, 16);
      v = (v > t) ? v : t;
      t = (unsigned)__shfl_xor((int)v, 32);
      v = (v > t) ? v : t;
      pk[nt] = v;
    }

    // Writers: lanes 0..15 (q=0) own batch col nt*16+lane for all nt, and
    // hold the matching inv_x[nt] (their own wl == lane). No barrier needed:
    // each wave writes only its own stage rows; hist bins are atomic.
    if (lane < 16) {
#pragma unroll
      for (int nt = 0; nt < 4; ++nt) {
        const unsigned p = pk[nt];
        const float val = (__uint_as_float(p & 0xFFFFFFC0u) - BIAS) * inv_x[nt];
        stage[(w * 64 + nt * 16 + lane) * NC_BLK + ci] = (_Float16)val;
        atomicAdd(&hist[ci * NLEAF + (int)(p & 63u)], 1u);
      }
    }
  }

  __syncthreads();  // stage writes visible to all

  // Coalesced cos flush: rows [b_base,+512) x cols [c_base,+4).
  // Thread t owns row t: 8B stage read (contiguous), float4 global write.
  {
    half4h_t h = *(const half4h_t*)&stage[tid * NC_BLK];
    float4_t v;
    v.x = (float)h[0]; v.y = (float)h[1]; v.z = (float)h[2]; v.w = (float)h[3];
    *(float4_t*)&cos_out[(size_t)(b_base + tid) * NCATS + c_base] = v;
  }

  // Flush histogram (exact: integer-valued float atomics).
  if (tid < NC_BLK * NLEAF) {
    const unsigned v = hist[tid];
    if (v) atomicAdd(&counts_out[c_base * NLEAF + tid], (float)v);
  }
}

extern "C" void kernel_launch(void* const* d_in, const int* in_sizes, int n_in,
                              void* d_out, int out_size, void* d_ws, size_t ws_size,
                              hipStream_t stream) {
  const float* x   = (const float*)d_in[0];
  const float* e   = (const float*)d_in[1];
  const float* cin = (const float*)d_in[2];

  const int B = in_sizes[0] / D;                 // 65536
  const int erows = in_sizes[1] / D;             // 4096
  float* cos_out = (float*)d_out;                // [B][64]
  float* counts_out = cos_out + (size_t)B * NCATS;
  char* e16 = (char*)d_ws;                       // 4096*256B = 1 MB swizzled fp16 E

  prep_e_kernel<<<erows / 16, 256, 0, stream>>>(e, e16, cin, counts_out);
  main_kernel<<<(B / BM) * (NCATS / NC_BLK), 512, 0, stream>>>(x, e16, cos_out, counts_out);
}

// Round 7
// 140.234 us; speedup vs baseline: 1.2772x; 1.1218x over previous
//
#include <hip/hip_runtime.h>
#include <stdint.h>
#include <stddef.h>

// Problem constants (fixed by the reference):
//   x:[B=65536][D=128] f32, E:[C=64][L=64][D=128] f32, counts:[64][64] f32
//   out0 = max_l cos(x_b, E_{c,l})  [B][C]
//   out1 = counts + bincount of argmax_l  [C][L]
#define D      128
#define NCATS  64
#define NLEAF  64
#define NC_BLK 4     // categories per block (c-split x16): ALL tiles LDS-resident
#define BM     512   // rows per block (8 waves x 64 batch cols)
#define BIAS   32.0f // dot ~ N(0,1) -> biased value positive -> uint order == float order

// Workspace layout: e16 [0,1MB) | x16 [1MB,17MB) | xinv [17MB,17.25MB)
#define WS_E16_BYTES   (1u << 20)
#define WS_X16_BYTES   (16u << 20)
#define WS_XINV_BYTES  (65536u * 4u)
#define WS_NEEDED      ((size_t)WS_E16_BYTES + WS_X16_BYTES + WS_XINV_BYTES)

typedef _Float16 half8_t  __attribute__((ext_vector_type(8)));
typedef _Float16 half4h_t __attribute__((ext_vector_type(4)));
typedef float    float4_t __attribute__((ext_vector_type(4)));

__device__ __forceinline__ void async_ld16(const void* g, void* l) {
  __builtin_amdgcn_global_load_lds((const __attribute__((address_space(1))) uint32_t*)g,
                                   (__attribute__((address_space(3))) uint32_t*)l,
                                   16, 0, 0);
}

__device__ __forceinline__ unsigned umax2(unsigned a, unsigned b) { return a > b ? a : b; }
// Nested so the compiler fuses to v_max3_u32.
__device__ __forceinline__ unsigned umax3(unsigned a, unsigned b, unsigned c) {
  return umax2(umax2(a, b), c);
}

// ---------------------------------------------------------------------------
// Prep:
//  blocks [0,256): E rows -> unit-normalized fp16, LDS-swizzle pre-baked
//    (chunk' = chunk ^ (row&7)); seeds counts_out from cin (d_out poisoned).
//  blocks [256,4352) (XP mode only): x rows -> RAW fp16 in 16-row tiles
//    (addr = g*4096 + chunk*256 + (row&15)*16 -> main reads 1KB contiguous
//    per fragment instr) + inv_x[row] (f32, from f32 data — same math main
//    used to do inline; bit-identical results).
// R14 rationale: main paid the x cvt+norm chain 16x redundantly (c-split),
// VALUBusy 38% top pipe; and 16x re-read of f32 x = 4MB/XCD = exactly L2 ->
// thrash (FETCH 118MB). fp16 x halves the working set to 2MB/XCD.
// ---------------------------------------------------------------------------
__global__ __launch_bounds__(256) void prep_kernel(const float* __restrict__ e,
                                                   const float* __restrict__ xf,
                                                   char* __restrict__ e16,
                                                   char* __restrict__ x16,
                                                   float* __restrict__ xinv,
                                                   const float* __restrict__ cin,
                                                   float* __restrict__ counts_out) {
  const int t  = threadIdx.x;
  const int rl = t >> 4;  // row within this block's 16
  const int cc = t & 15;  // 16B chunk (8 halfs) within row

  if (blockIdx.x < 256) {
    const int row = blockIdx.x * 16 + rl;
    const float* src = e + (size_t)row * D + cc * 8;
    float4_t v0 = *(const float4_t*)src;
    float4_t v1 = *(const float4_t*)(src + 4);
    float ss = v0.x*v0.x + v0.y*v0.y + v0.z*v0.z + v0.w*v0.w +
               v1.x*v1.x + v1.y*v1.y + v1.z*v1.z + v1.w*v1.w;
    ss += __shfl_xor(ss, 1);
    ss += __shfl_xor(ss, 2);
    ss += __shfl_xor(ss, 4);
    ss += __shfl_xor(ss, 8);
    const float inv = 1.0f / fmaxf(sqrtf(ss), 1e-8f);
    half8_t h;
    h[0] = (_Float16)(v0.x * inv); h[1] = (_Float16)(v0.y * inv);
    h[2] = (_Float16)(v0.z * inv); h[3] = (_Float16)(v0.w * inv);
    h[4] = (_Float16)(v1.x * inv); h[5] = (_Float16)(v1.y * inv);
    h[6] = (_Float16)(v1.z * inv); h[7] = (_Float16)(v1.w * inv);
    const int dc = cc ^ (rl & 7);  // swizzle: row&7 == rl&7 (16-row blocks)
    *(half8_t*)(e16 + (size_t)row * 256 + dc * 16) = h;
    if (blockIdx.x < (NCATS * NLEAF) / 256)
      counts_out[blockIdx.x * 256 + t] = cin[blockIdx.x * 256 + t];
  } else {
    const int g   = blockIdx.x - 256;     // 16-row group 0..4095
    const int row = g * 16 + rl;          // 0..65535
    const float* src = xf + (size_t)row * D + cc * 8;
    float4_t v0 = *(const float4_t*)src;
    float4_t v1 = *(const float4_t*)(src + 4);
    float ss = v0.x*v0.x + v0.y*v0.y + v0.z*v0.z + v0.w*v0.w +
               v1.x*v1.x + v1.y*v1.y + v1.z*v1.z + v1.w*v1.w;
    ss += __shfl_xor(ss, 1);
    ss += __shfl_xor(ss, 2);
    ss += __shfl_xor(ss, 4);
    ss += __shfl_xor(ss, 8);
    const float inv = 1.0f / fmaxf(sqrtf(ss), 1e-8f);
    half8_t h;  // RAW fp16 (main multiplies inv at epilogue, as before)
    h[0] = (_Float16)v0.x; h[1] = (_Float16)v0.y;
    h[2] = (_Float16)v0.z; h[3] = (_Float16)v0.w;
    h[4] = (_Float16)v1.x; h[5] = (_Float16)v1.y;
    h[6] = (_Float16)v1.z; h[7] = (_Float16)v1.w;
    *(half8_t*)(x16 + (size_t)g * 4096 + cc * 256 + rl * 16) = h;
    if (cc == 0) xinv[row] = inv;
  }
}

// ---------------------------------------------------------------------------
// Main (R14): R13 chassis (NC_BLK=4 all-LDS-resident, ONE barrier, barrier-
// free ci loop, (512,3), VGPR must stay <=64 — R11/R12 both died crossing it)
// + three VALU cuts driven by R13 counters (VALUBusy 38% top pipe):
//  * XP: bfrag loaded as fp16 from prep'd x16 (16 coalesced 1KB loads, no
//    cvt/norm/shuffle prologue); inv_x from xinv. Halves x L2 working set.
//  * max3 pack: v_max3_u32 tree, -32 VALU/ci/wave.
//  * 64-lane writers: lane (q,wl) handles nt=q via constant-index selects
//    (transient temps only) -> 1 stage write + 1 hist atomic instr, not 4.
// ---------------------------------------------------------------------------
template <bool XP>
__global__ __launch_bounds__(512, 3) void main_kernel(const float* __restrict__ x,
                                                      const char* __restrict__ e16,
                                                      const char* __restrict__ x16,
                                                      const float* __restrict__ xinv,
                                                      float* __restrict__ cos_out,
                                                      float* __restrict__ counts_out) {
  __shared__ __align__(16) char ebuf[NC_BLK][16384];     // 64 KB, swizzled rows
  __shared__ unsigned hist[NC_BLK * NLEAF];              // 1 KB
  __shared__ __align__(16) _Float16 stage[BM * NC_BLK];  // 4 KB, 8 B/row

  const int tid  = threadIdx.x;
  const int w    = tid >> 6;    // wave 0..7
  const int lane = tid & 63;
  const int q    = lane >> 4;   // MFMA quad
  const int wl   = lane & 15;

  // XCD-aware decode: bid = c_idx*128 + rb_local*8 + xcd.
  const int xcd    = blockIdx.x & 7;
  const int rb     = xcd * 16 + ((blockIdx.x >> 3) & 15);
  const int c_base = (blockIdx.x >> 7) * NC_BLK;
  const int b_base = rb * BM;

  // Stage ALL 4 tiles now: wave w -> tile w>>1, half w&1 (8KB each, 8 loads).
  {
    const char* g = e16 + (size_t)(c_base + (w >> 1)) * 16384 + (w & 1) * 8192 + lane * 16;
    char* l = &ebuf[w >> 1][(w & 1) * 8192 + lane * 16];
#pragma unroll
    for (int j = 0; j < 8; ++j) async_ld16(g + j * 1024, l + j * 1024);
  }

  if (tid < NC_BLK * NLEAF) hist[tid] = 0;

  // B = x fragments (verified lane layout: B[n=lane&15][k=quad*8+j]):
  // tile nt covers batch rows b_base + w*64 + nt*16 + [0,16).
  half8_t bfrag[4][4];
  float inv_x[4];
  if constexpr (XP) {
    const size_t gbase = ((size_t)b_base >> 4) + (size_t)w * 4;
#pragma unroll
    for (int nt = 0; nt < 4; ++nt) {
      const char* xr = x16 + (gbase + nt) * 4096 + q * 256 + wl * 16;
#pragma unroll
      for (int s = 0; s < 4; ++s)
        bfrag[nt][s] = *(const half8_t*)(xr + s * 1024);  // 1KB/instr coalesced
      inv_x[nt] = xinv[b_base + w * 64 + nt * 16 + wl];
    }
  } else {
#pragma unroll
    for (int nt = 0; nt < 4; ++nt) {
      const int row = b_base + w * 64 + nt * 16 + wl;
      const float* xr = x + (size_t)row * D;
      float ss = 0.f;
#pragma unroll
      for (int s = 0; s < 4; ++s) {
        const float* p = xr + s * 32 + q * 8;
        float4_t v0 = *(const float4_t*)p;
        float4_t v1 = *(const float4_t*)(p + 4);
        half8_t h;
        h[0] = (_Float16)v0.x; h[1] = (_Float16)v0.y;
        h[2] = (_Float16)v0.z; h[3] = (_Float16)v0.w;
        h[4] = (_Float16)v1.x; h[5] = (_Float16)v1.y;
        h[6] = (_Float16)v1.z; h[7] = (_Float16)v1.w;
        bfrag[nt][s] = h;
        ss += v0.x*v0.x + v0.y*v0.y + v0.z*v0.z + v0.w*v0.w +
              v1.x*v1.x + v1.y*v1.y + v1.z*v1.z + v1.w*v1.w;
      }
      ss += __shfl_xor(ss, 16);
      ss += __shfl_xor(ss, 32);
      inv_x[nt] = 1.0f / fmaxf(sqrtf(ss), 1e-8f);
    }
  }

  // A = E LDS addresses (rt = leaf tile): row (rt*16+wl), chunk
  // (q+4s)^(wl&7) [prep pre-swizzled].
  int rowbase[4], xoff[4];
#pragma unroll
  for (int rt = 0; rt < 4; ++rt) rowbase[rt] = (rt * 16 + wl) * 256;
#pragma unroll
  for (int s = 0; s < 4; ++s) xoff[s] = ((q + 4 * s) ^ (wl & 7)) * 16;

  const unsigned idq = (unsigned)(q << 2);  // leaf-index bits {2,3} (lane const)
  const float4_t bias4 = {BIAS, BIAS, BIAS, BIAS};

  __syncthreads();  // ONE barrier: drains tile DMA (vmcnt0) + hist init

  // ----- barrier-free, wait-free ci loop -----
#pragma unroll
  for (int ci = 0; ci < NC_BLK; ++ci) {
    const char* cur = ebuf[ci];

    // rt-outer: acc[4] (one per batch tile nt) live at a time. C/D layout:
    // col = lane&15 = batch-within-tile, row = q*4+reg = leaf-within-tile.
    // Keys carry leaf idx bits {0,1}=reg, {4,5}=rt at pack time; bits {2,3}
    // (=q) are zero in-lane and OR'd once before the cross-lane combine.
    unsigned pk[4];
    __builtin_amdgcn_s_setprio(1);
#pragma unroll
    for (int rt = 0; rt < 4; ++rt) {
      float4_t acc[4];
#pragma unroll
      for (int s = 0; s < 4; ++s) {
        half8_t ef = *(const half8_t*)(cur + rowbase[rt] + xoff[s]);
#pragma unroll
        for (int nt = 0; nt < 4; ++nt)
          acc[nt] = __builtin_amdgcn_mfma_f32_16x16x32_f16(
              ef, bfrag[nt][s], (s == 0) ? bias4 : acc[nt], 0, 0, 0);
      }
      // Pack via max3 tree (keys are positive floats: dot+BIAS ~ 32+-5).
#pragma unroll
      for (int nt = 0; nt < 4; ++nt) {
        const unsigned k0 = (__float_as_uint(acc[nt][0]) & 0xFFFFFFC0u) | (unsigned)(rt * 16 + 0);
        const unsigned k1 = (__float_as_uint(acc[nt][1]) & 0xFFFFFFC0u) | (unsigned)(rt * 16 + 1);
        const unsigned k2 = (__float_as_uint(acc[nt][2]) & 0xFFFFFFC0u) | (unsigned)(rt * 16 + 2);
        const unsigned k3 = (__float_as_uint(acc[nt][3]) & 0xFFFFFFC0u) | (unsigned)(rt * 16 + 3);
        const unsigned m  = umax3(k0, k1, k2);
        pk[nt] = (rt == 0) ? umax2(m, k3) : umax3(m, k3, pk[nt]);
      }
    }
    __builtin_amdgcn_s_setprio(0);

    // Cross-lane: combine the 4 quads of this batch col. EXPLICIT TEMPS,
    // unconditional shuffles (R3 lesson: never a cross-lane op in a ternary).
#pragma unroll
    for (int nt = 0; nt < 4; ++nt) {
      unsigned v = pk[nt] | idq;
      unsigned t = (unsigned)__shfl_xor((int)v, 16);
      v = (v > t) ? v : t;
      t = (unsigned)__shfl_xor((int)v, 32);
      v = (v > t) ? v : t;
      pk[nt] = v;  // quad-uniform for this wl
    }

    // Writers spread over all 64 lanes: lane (q,wl) handles nt=q. pk[q] is
    // quad-uniform; inv_x[nt] is wl-determined (q-independent) -> every lane
    // holds the right inv. Constant-index selects only (no runtime indexing).
    {
      const unsigned pk01 = (q == 0) ? pk[0] : pk[1];
      const unsigned pk23 = (q == 2) ? pk[2] : pk[3];
      const unsigned pkq  = (q < 2) ? pk01 : pk23;
      const float    iv01 = (q == 0) ? inv_x[0] : inv_x[1];
      const float    iv23 = (q == 2) ? inv_x[2] : inv_x[3];
      const float    invq = (q < 2) ? iv01 : iv23;
      const float val = (__uint_as_float(pkq & 0xFFFFFFC0u) - BIAS) * invq;
      stage[tid * NC_BLK + ci] = (_Float16)val;  // row w*64+q*16+wl == tid
      atomicAdd(&hist[ci * NLEAF + (int)(pkq & 63u)], 1u);
    }
  }

  __syncthreads();  // stage writes visible to all

  // Coalesced cos flush: rows [b_base,+512) x cols [c_base,+4).
  // Thread t owns row t: 8B stage read (contiguous), float4 global write.
  {
    half4h_t h = *(const half4h_t*)&stage[tid * NC_BLK];
    float4_t v;
    v.x = (float)h[0]; v.y = (float)h[1]; v.z = (float)h[2]; v.w = (float)h[3];
    *(float4_t*)&cos_out[(size_t)(b_base + tid) * NCATS + c_base] = v;
  }

  // Flush histogram (exact: integer-valued float atomics).
  if (tid < NC_BLK * NLEAF) {
    const unsigned v = hist[tid];
    if (v) atomicAdd(&counts_out[c_base * NLEAF + tid], (float)v);
  }
}

extern "C" void kernel_launch(void* const* d_in, const int* in_sizes, int n_in,
                              void* d_out, int out_size, void* d_ws, size_t ws_size,
                              hipStream_t stream) {
  const float* x   = (const float*)d_in[0];
  const float* e   = (const float*)d_in[1];
  const float* cin = (const float*)d_in[2];

  const int B = in_sizes[0] / D;                 // 65536
  float* cos_out = (float*)d_out;                // [B][64]
  float* counts_out = cos_out + (size_t)B * NCATS;

  char*  e16  = (char*)d_ws;                     // 1 MB swizzled fp16 E
  char*  x16  = e16 + WS_E16_BYTES;              // 16 MB tiled fp16 x
  float* xinv = (float*)(x16 + WS_X16_BYTES);    // 256 KB f32 inv-norms

  const bool xp = (ws_size >= WS_NEEDED);
  const int prep_grid = xp ? (256 + B / 16) : 256;
  prep_kernel<<<prep_grid, 256, 0, stream>>>(e, x, e16, x16, xinv, cin, counts_out);

  const int main_grid = (B / BM) * (NCATS / NC_BLK);  // 2048
  if (xp)
    main_kernel<true><<<main_grid, 512, 0, stream>>>(x, e16, x16, xinv, cos_out, counts_out);
  else
    main_kernel<false><<<main_grid, 512, 0, stream>>>(x, e16, x16, xinv, cos_out, counts_out);
}